// Round 5
// baseline (354.387 us; speedup 1.0000x reference)
//
#include <hip/hip_runtime.h>

// ============================================================================
// FusedConv v5: v4's fast skeleton (transposed dataflow, 64-edge tiles,
// packed-u32 LDS, 3 barriers, in-register G3 contraction) with all VALUE-
// producing subsystems reverted to v1's proven versions:
//   - prep: v1's scalar weight transposes + ebf (bf16 edges) staging
//   - gelu: exact erff
//   - tmp:  computed from bf16-rounded feats/basis (v1 arithmetic)
// Purpose: isolate the deterministic absmax=8.0 corruption of v2-v4 while
// keeping the fast structure.
// ============================================================================

typedef __bf16   bf16x8 __attribute__((ext_vector_type(8)));
typedef float    f32x4  __attribute__((ext_vector_type(4)));
typedef unsigned u32x2  __attribute__((ext_vector_type(2)));
typedef unsigned u32x4  __attribute__((ext_vector_type(4)));

union FragU { u32x4 u; bf16x8 h; };
union PackU { __bf16 h[2]; unsigned u; };

#define TE 64
#define E_TOT 65536
#define NBLK (E_TOT / TE)

__device__ __forceinline__ f32x4 mfma16(bf16x8 a, bf16x8 b, f32x4 c) {
    return __builtin_amdgcn_mfma_f32_16x16x32_bf16(a, b, c, 0, 0, 0);
}

__device__ __forceinline__ unsigned packbf2(float a, float b) {
    PackU cv; cv.h[0] = (__bf16)a; cv.h[1] = (__bf16)b; return cv.u;
}
__device__ __forceinline__ float lo16f(unsigned v) {
    union { unsigned u; float f; } x; x.u = v << 16; return x.f;
}
__device__ __forceinline__ float hi16f(unsigned v) {
    union { unsigned u; float f; } x; x.u = v & 0xffff0000u; return x.f;
}

// v1's exact gelu
__device__ __forceinline__ float gelu_f(float x) {
    return 0.5f * x * (1.0f + erff(x * 0.7071067811865476f));
}

// ---- ws layout (bytes) ---- (v1's exact layout)
#define WS_W1T   0u         // 256 x 32  bf16 (n-major)   16384 B
#define WS_W2T   16384u     // 256 x 256 bf16 (n-major)  131072 B
#define WS_W3KT  147456u    // 768 x 256 bf16 (n-major)  393216 B
#define WS_EBF   540672u    // E x 32 bf16               4194304 B

#define N_W1T  8192
#define N_W2T  65536
#define N_W3KT 196608
#define N_EBF  2097152
#define PREP_TOT (N_W1T + N_W2T + N_W3KT + N_EBF)

// ====================== prep: v1's exact scalar version =====================
__global__ __launch_bounds__(256) void prep_kernel(
    const float* __restrict__ edges, const float* __restrict__ W1,
    const float* __restrict__ W2, const float* __restrict__ W3,
    __bf16* __restrict__ W1T, __bf16* __restrict__ W2T,
    __bf16* __restrict__ W3kT, __bf16* __restrict__ ebf)
{
    int stride = gridDim.x * blockDim.x;
    for (int idx = blockIdx.x * blockDim.x + threadIdx.x; idx < PREP_TOT; idx += stride) {
        if (idx < N_W1T) {
            int n = idx >> 5, k = idx & 31;
            W1T[idx] = (__bf16)W1[k * 256 + n];
        } else if (idx < N_W1T + N_W2T) {
            int t = idx - N_W1T; int n = t >> 8, k = t & 255;
            W2T[t] = (__bf16)W2[k * 256 + n];
        } else if (idx < N_W1T + N_W2T + N_W3KT) {
            int t = idx - (N_W1T + N_W2T); int n = t >> 8, k = t & 255;
            W3kT[t] = (__bf16)W3[k * 1536 + 768 + n];
        } else {
            int t = idx - (N_W1T + N_W2T + N_W3KT);
            ebf[t] = (__bf16)edges[t];
        }
    }
}

// ================================ fused =====================================
// LDS (uint units): h1f [0,8192): [kc][e][4u]; h2f [8192,16384): same.
// After B2, [0,4608) reused as tmp_s[e][d][24u] (J pairs).
__global__ __launch_bounds__(256) void fused_kernel(
    const __bf16* __restrict__ ebf, const __bf16* __restrict__ W1T,
    const __bf16* __restrict__ W2T, const __bf16* __restrict__ W3kT,
    const float* __restrict__ b1, const float* __restrict__ b2,
    const float* __restrict__ feats, const float* __restrict__ basis,
    float* __restrict__ out)
{
    __shared__ unsigned smem[16384];     // 64 KiB
    unsigned* h1f   = smem;              // uint idx: (kc*64+e)*4 + j/2
    unsigned* h2f   = smem + 8192;
    unsigned* tmp_s = smem;              // uint idx: e*72 + d*24 + J/2

    const int tid = threadIdx.x;
    const int w = tid >> 6;      // wave 0..3
    const int l = tid & 63;
    const int c = l & 15;
    const int q = l >> 4;        // 0..3
    const int eb = blockIdx.x * TE;
    const f32x4 zero = {0.f, 0.f, 0.f, 0.f};

    // ---------------- G1t: h1T rows n = w*64 + mt*16 + c --------------------
    bf16x8 bfr[4];
    #pragma unroll
    for (int nt = 0; nt < 4; ++nt)
        bfr[nt] = *(const bf16x8*)(ebf + (unsigned)(eb + nt * 16 + c) * 32 + q * 8);

    f32x4 acc1[4][4];
    #pragma unroll
    for (int mt = 0; mt < 4; ++mt)
        #pragma unroll
        for (int nt = 0; nt < 4; ++nt) acc1[mt][nt] = zero;
    #pragma unroll
    for (int mt = 0; mt < 4; ++mt) {
        bf16x8 afr = *(const bf16x8*)(W1T + (unsigned)(w * 64 + mt * 16 + c) * 32 + q * 8);
        #pragma unroll
        for (int nt = 0; nt < 4; ++nt) acc1[mt][nt] = mfma16(afr, bfr[nt], acc1[mt][nt]);
    }
    // epilogue: lane holds rows n = nbase+r (r=0..3), col e = nt*16+c
    #pragma unroll
    for (int mt = 0; mt < 4; ++mt) {
        int nbase = w * 64 + mt * 16 + 4 * q;
        float4 bv = *(const float4*)(b1 + nbase);
        int kc = nbase >> 3, jh = (q & 1) * 2;       // uint offset within 4-uint row
        #pragma unroll
        for (int nt = 0; nt < 4; ++nt) {
            int e = nt * 16 + c;
            u32x2 pk;
            pk[0] = packbf2(gelu_f(acc1[mt][nt][0] + bv.x), gelu_f(acc1[mt][nt][1] + bv.y));
            pk[1] = packbf2(gelu_f(acc1[mt][nt][2] + bv.z), gelu_f(acc1[mt][nt][3] + bv.w));
            *(u32x2*)(h1f + (unsigned)(kc * 64 + e) * 4 + jh) = pk;
        }
    }
    __syncthreads();   // B1: h1f ready

    // ---------------- G2t: K=256 --------------------------------------------
    f32x4 acc2[4][4];
    #pragma unroll
    for (int mt = 0; mt < 4; ++mt)
        #pragma unroll
        for (int nt = 0; nt < 4; ++nt) acc2[mt][nt] = zero;
    #pragma unroll
    for (int ks = 0; ks < 8; ++ks) {
        bf16x8 bfr2[4];
        #pragma unroll
        for (int nt = 0; nt < 4; ++nt) {
            FragU fu;
            fu.u = *(const u32x4*)(h1f + (unsigned)((ks * 4 + q) * 64 + nt * 16 + c) * 4);
            bfr2[nt] = fu.h;
        }
        #pragma unroll
        for (int mt = 0; mt < 4; ++mt) {
            bf16x8 afr = *(const bf16x8*)(W2T + (unsigned)(w * 64 + mt * 16 + c) * 256 + ks * 32 + q * 8);
            #pragma unroll
            for (int nt = 0; nt < 4; ++nt) acc2[mt][nt] = mfma16(afr, bfr2[nt], acc2[mt][nt]);
        }
    }
    #pragma unroll
    for (int mt = 0; mt < 4; ++mt) {
        int nbase = w * 64 + mt * 16 + 4 * q;
        float4 bv = *(const float4*)(b2 + nbase);
        int kc = nbase >> 3, jh = (q & 1) * 2;
        #pragma unroll
        for (int nt = 0; nt < 4; ++nt) {
            int e = nt * 16 + c;
            u32x2 pk;
            pk[0] = packbf2(gelu_f(acc2[mt][nt][0] + bv.x), gelu_f(acc2[mt][nt][1] + bv.y));
            pk[1] = packbf2(gelu_f(acc2[mt][nt][2] + bv.z), gelu_f(acc2[mt][nt][3] + bv.w));
            *(u32x2*)(h2f + (unsigned)(kc * 64 + e) * 4 + jh) = pk;
        }
    }
    __syncthreads();   // B2: h1f area reusable; h2f ready

    // ------- tmp_s[e][d][J] (uint-packed J pairs), v1 value-path ------------
    // (inputs rounded to bf16 first, fp32 mul-add chain, result rounded bf16)
    {
        int e = tid >> 2, p = tid & 3;           // 4 threads per edge
        const float* fp = feats + (unsigned)(eb + e) * 48 + p * 12;
        float fv[12];
        #pragma unroll
        for (int j = 0; j < 12; ++j) fv[j] = (float)(__bf16)fp[j];
        const float* bp = basis + (unsigned)(eb + e) * 27;
        float bvv[27];
        #pragma unroll
        for (int i = 0; i < 27; ++i) bvv[i] = (float)(__bf16)bp[i];
        float tv[12][3];
        #pragma unroll
        for (int jj = 0; jj < 12; ++jj) {
            int i3 = (jj / 3) * 3, nf = jj % 3;
            #pragma unroll
            for (int d = 0; d < 3; ++d) {
                float s = 0.f;
                #pragma unroll
                for (int c2 = 0; c2 < 3; ++c2)
                    s += fv[i3 + c2] * bvv[c2 * 9 + nf * 3 + d];
                tv[jj][d] = s;
            }
        }
        #pragma unroll
        for (int d = 0; d < 3; ++d)
            #pragma unroll
            for (int u = 0; u < 6; ++u)
                tmp_s[(unsigned)e * 72 + d * 24 + p * 6 + u] =
                    packbf2(tv[2 * u][d], tv[2 * u + 1][d]);
    }
    __syncthreads();   // B3: tmp ready; from here LDS is READ-ONLY

    // ---------------- G3t + in-register contraction, 2 halves ---------------
    #pragma unroll 1
    for (int H = 0; H < 2; ++H) {
        f32x4 acc3[6][4];
        #pragma unroll
        for (int m6 = 0; m6 < 6; ++m6)
            #pragma unroll
            for (int nt = 0; nt < 4; ++nt) acc3[m6][nt] = zero;
        #pragma unroll
        for (int ks = 0; ks < 8; ++ks) {
            bf16x8 bfr3[4];
            #pragma unroll
            for (int nt = 0; nt < 4; ++nt) {
                FragU fu;
                fu.u = *(const u32x4*)(h2f + (unsigned)((ks * 4 + q) * 64 + nt * 16 + c) * 4);
                bfr3[nt] = fu.h;
            }
            #pragma unroll
            for (int m6 = 0; m6 < 6; ++m6) {
                int row = w * 192 + H * 96 + m6 * 16 + c;
                bf16x8 afr = *(const bf16x8*)(W3kT + (unsigned)row * 256 + ks * 32 + q * 8);
                #pragma unroll
                for (int nt = 0; nt < 4; ++nt) acc3[m6][nt] = mfma16(afr, bfr3[nt], acc3[m6][nt]);
            }
        }
        // lane (q,c) holds rp[e=nt*16+c][J=mm*16+4q+r] for o = w*4+H*2+ol
        #pragma unroll
        for (int nt = 0; nt < 4; ++nt) {
            int e = nt * 16 + c;
            float tvv[3][3][4];
            #pragma unroll
            for (int d = 0; d < 3; ++d)
                #pragma unroll
                for (int mm = 0; mm < 3; ++mm) {
                    u32x2 pk = *(const u32x2*)(tmp_s + (unsigned)e * 72 + d * 24 + mm * 8 + 2 * q);
                    tvv[d][mm][0] = lo16f(pk[0]); tvv[d][mm][1] = hi16f(pk[0]);
                    tvv[d][mm][2] = lo16f(pk[1]); tvv[d][mm][3] = hi16f(pk[1]);
                }
            float res[2][3];
            #pragma unroll
            for (int ol = 0; ol < 2; ++ol)
                #pragma unroll
                for (int d = 0; d < 3; ++d) {
                    float s = 0.f;
                    #pragma unroll
                    for (int mm = 0; mm < 3; ++mm)
                        #pragma unroll
                        for (int r = 0; r < 4; ++r)
                            s = fmaf(acc3[ol * 3 + mm][nt][r], tvv[d][mm][r], s);
                    res[ol][d] = s;
                }
            #pragma unroll
            for (int ol = 0; ol < 2; ++ol)
                #pragma unroll
                for (int d = 0; d < 3; ++d) {
                    float v = res[ol][d];
                    v += __shfl_xor(v, 16, 64);
                    v += __shfl_xor(v, 32, 64);
                    res[ol][d] = v;
                }
            if (q == 0) {
                float* op = out + (unsigned)(eb + e) * 48 + (unsigned)(w * 4 + H * 2) * 3;
                op[0] = res[0][0]; op[1] = res[0][1]; op[2] = res[0][2];
                op[3] = res[1][0]; op[4] = res[1][1]; op[5] = res[1][2];
            }
        }
    }
}

extern "C" void kernel_launch(void* const* d_in, const int* in_sizes, int n_in,
                              void* d_out, int out_size, void* d_ws, size_t ws_size,
                              hipStream_t stream) {
    const float* edges = (const float*)d_in[0];
    const float* feats = (const float*)d_in[1];
    const float* basis = (const float*)d_in[2];
    const float* W1    = (const float*)d_in[3];
    const float* b1    = (const float*)d_in[4];
    const float* W2    = (const float*)d_in[5];
    const float* b2    = (const float*)d_in[6];
    const float* W3    = (const float*)d_in[7];
    float* out = (float*)d_out;

    __bf16* W1T  = (__bf16*)((char*)d_ws + WS_W1T);
    __bf16* W2T  = (__bf16*)((char*)d_ws + WS_W2T);
    __bf16* W3kT = (__bf16*)((char*)d_ws + WS_W3KT);
    __bf16* ebf  = (__bf16*)((char*)d_ws + WS_EBF);

    prep_kernel<<<1024, 256, 0, stream>>>(edges, W1, W2, W3, W1T, W2T, W3kT, ebf);
    fused_kernel<<<NBLK, 256, 0, stream>>>(ebf, W1T, W2T, W3kT, b1, b2,
                                           feats, basis, out);
}